// Round 7
// baseline (209.710 us; speedup 1.0000x reference)
//
#include <hip/hip_runtime.h>

#define HH 160
#define WW 160
#define DD 16
#define NG 8192
#define VOXEL 0.4f

// tiles: 20 x 20 x 4 (each 8x8x4 voxels) = 1600 tiles
#define TTX 20
#define TTY 20
#define TTZ 4
#define NTILES (TTX * TTY * TTZ)
#define CAP 256   // max survivors per tile (lambda ~61, Poisson max ~110)

// d_ws layout:
//   pack     : 8192 * 4 float4 (64 B/gaussian)   = 512 KB @ 0
//   tileCnt  : NTILES int (6.4 KB)               @ 512 KB
//   tileList : NTILES * CAP int (1.6 MB)         @ 520 KB
// pack per gaussian:
//   p0 = (mu.x, mu.y, mu.z, opacity)
//   p1 = (3sx,  3sy,  3sz,  ci00)
//   p2 = (ci01, ci02, ci11, ci12)
//   p3 = (ci22, 0, 0, 0)

__global__ __launch_bounds__(64) void gv_precompute_bin(
    const float* __restrict__ means, const float* __restrict__ opac,
    const float* __restrict__ scales, const float* __restrict__ rots,
    float4* __restrict__ pack, int* __restrict__ tileCnt,
    int* __restrict__ tileList) {
  int g = blockIdx.x * 64 + threadIdx.x;
  if (g >= NG) return;
  float qw = rots[g * 4 + 0], qx = rots[g * 4 + 1];
  float qy = rots[g * 4 + 2], qz = rots[g * 4 + 3];
  float inv = rsqrtf(qw * qw + qx * qx + qy * qy + qz * qz);
  qw *= inv; qx *= inv; qy *= inv; qz *= inv;
  float R[3][3];
  R[0][0] = 1.f - 2.f * (qy * qy + qz * qz);
  R[0][1] = 2.f * (qx * qy - qw * qz);
  R[0][2] = 2.f * (qx * qz + qw * qy);
  R[1][0] = 2.f * (qx * qy + qw * qz);
  R[1][1] = 1.f - 2.f * (qx * qx + qz * qz);
  R[1][2] = 2.f * (qy * qz - qw * qx);
  R[2][0] = 2.f * (qx * qz - qw * qy);
  R[2][1] = 2.f * (qy * qz + qw * qx);
  R[2][2] = 1.f - 2.f * (qx * qx + qy * qy);
  float sx = scales[g * 3 + 0], sy = scales[g * 3 + 1], sz = scales[g * 3 + 2];
  float s2[3] = {sx * sx, sy * sy, sz * sz};
  float is2[3] = {1.f / s2[0], 1.f / s2[1], 1.f / s2[2]};
  float cov00 = 0.f, cov11 = 0.f, cov22 = 0.f;
  float ci00 = 0.f, ci01 = 0.f, ci02 = 0.f, ci11 = 0.f, ci12 = 0.f, ci22 = 0.f;
#pragma unroll
  for (int c = 0; c < 3; c++) {
    cov00 += R[0][c] * R[0][c] * s2[c];
    cov11 += R[1][c] * R[1][c] * s2[c];
    cov22 += R[2][c] * R[2][c] * s2[c];
    ci00 += R[0][c] * R[0][c] * is2[c];
    ci01 += R[0][c] * R[1][c] * is2[c];
    ci02 += R[0][c] * R[2][c] * is2[c];
    ci11 += R[1][c] * R[1][c] * is2[c];
    ci12 += R[1][c] * R[2][c] * is2[c];
    ci22 += R[2][c] * R[2][c] * is2[c];
  }
  float mx = means[g * 3 + 0], my = means[g * 3 + 1], mz = means[g * 3 + 2];
  float bx = 3.f * sqrtf(cov00), by = 3.f * sqrtf(cov11), bz = 3.f * sqrtf(cov22);
  float4* p = pack + (size_t)g * 4;
  p[0] = make_float4(mx, my, mz, opac[g]);
  p[1] = make_float4(bx, by, bz, ci00);
  p[2] = make_float4(ci01, ci02, ci11, ci12);
  p[3] = make_float4(ci22, 0.f, 0.f, 0.f);

  // voxel-center index ranges covered by bbox (with float-slop margin)
  const float eps = 1e-4f;
  int i0 = (int)ceilf((mx - bx + 32.f) * 2.5f - 0.5f - eps);
  int i1 = (int)floorf((mx + bx + 32.f) * 2.5f - 0.5f + eps);
  int j0 = (int)ceilf((my - by + 32.f) * 2.5f - 0.5f - eps);
  int j1 = (int)floorf((my + by + 32.f) * 2.5f - 0.5f + eps);
  int k0 = (int)ceilf((mz - bz + 1.f) * 2.5f - 0.5f - eps);
  int k1 = (int)floorf((mz + bz + 1.f) * 2.5f - 0.5f + eps);
  i0 = max(i0, 0); i1 = min(i1, HH - 1);
  j0 = max(j0, 0); j1 = min(j1, WW - 1);
  k0 = max(k0, 0); k1 = min(k1, DD - 1);
  if (i0 > i1 || j0 > j1 || k0 > k1) return;
  int ti0 = i0 >> 3, ti1 = i1 >> 3;
  int tj0 = j0 >> 3, tj1 = j1 >> 3;
  int tk0 = k0 >> 2, tk1 = k1 >> 2;
  for (int ti = ti0; ti <= ti1; ti++)
    for (int tj = tj0; tj <= tj1; tj++)
      for (int tk = tk0; tk <= tk1; tk++) {
        int t = (ti * TTY + tj) * TTZ + tk;
        int pos = atomicAdd(&tileCnt[t], 1);
        if (pos < CAP) tileList[t * CAP + pos] = g;
      }
}

// Voxelize: VECTOR-load (vmcnt) ping-pong pipeline.
// SMEM completes out-of-order -> any s_load wait is lgkmcnt(0) which drains
// prefetches; so gaussian data is loaded via global_load_dwordx4 (in-order
// vmcnt, partial waits OK). Index comes from one coalesced list read per
// 64 gaussians, broadcast in-register with __shfl (keeps addresses in
// VGPRs -> backend cannot re-scalarize the loads).
#define LOADST(Pa, Pb, Pc, Pd, Pf, gg)                     \
  do {                                                     \
    const float4* _p = pack + (size_t)(gg) * 4;            \
    Pa = _p[0]; Pb = _p[1]; Pc = _p[2]; Pd = _p[3];        \
    const float4* _f = feats + (size_t)(gg) * 8;           \
    _Pragma("unroll")                                      \
    for (int f = 0; f < 8; f++) Pf[f] = _f[f];             \
  } while (0)

#define COMPUTE(Pa, Pb, Pc, Pd, Pf)                                       \
  do {                                                                    \
    float dx = px - Pa.x, dy = py - Pa.y, dz = pz - Pa.z;                 \
    bool in = (fabsf(dx) <= Pb.x) & (fabsf(dy) <= Pb.y) &                 \
              (fabsf(dz) <= Pb.z);                                        \
    if (__any(in)) {                                                      \
      float maha = Pb.w * dx * dx + Pc.z * dy * dy + Pd.x * dz * dz +     \
                   2.f * (Pc.x * dx * dy + Pc.y * dx * dz +               \
                          Pc.w * dy * dz);                                \
      float wgt = in ? Pa.w * __expf(-0.5f * maha) : 0.f;                 \
      _Pragma("unroll")                                                   \
      for (int f = 0; f < 8; f++) {                                       \
        acc[f].x += wgt * Pf[f].x;                                        \
        acc[f].y += wgt * Pf[f].y;                                        \
        acc[f].z += wgt * Pf[f].z;                                        \
        acc[f].w += wgt * Pf[f].w;                                        \
      }                                                                   \
    }                                                                     \
  } while (0)

__global__ __launch_bounds__(256) void gv_voxelize(
    const float4* __restrict__ pack, const float4* __restrict__ feats,
    const int* __restrict__ tileCnt, const int* __restrict__ tileList,
    float4* __restrict__ out) {
  int tid = threadIdx.x;
  int lane = tid & 63;
  int dk = tid & 3, dj = (tid >> 2) & 7, di = tid >> 5;
  int tk = blockIdx.x, tj = blockIdx.y, ti = blockIdx.z;
  int i = ti * 8 + di, j = tj * 8 + dj, k = tk * 4 + dk;

  float px = (i + 0.5f) * VOXEL - 32.f;
  float py = (j + 0.5f) * VOXEL - 32.f;
  float pz = (k + 0.5f) * VOXEL - 1.f;

  int t = (ti * TTY + tj) * TTZ + tk;
  int cnt = tileCnt[t];
  cnt = min(cnt, CAP);
  const int* __restrict__ lst = tileList + t * CAP;

  float4 acc[8];
#pragma unroll
  for (int f = 0; f < 8; f++) acc[f] = make_float4(0.f, 0.f, 0.f, 0.f);

  for (int base = 0; base < cnt; base += 64) {
    // one coalesced list read per 64 gaussians (always within CAP -> safe;
    // entries beyond cnt are stale but never consumed)
    int lv = lst[base + lane];
    int M = min(64, cnt - base);

    float4 Aa, Ab, Ac, Ad, Af[8];
    float4 Ba, Bb, Bc, Bd, Bf[8];

    int gA = __shfl(lv, 0);
    LOADST(Aa, Ab, Ac, Ad, Af, gA);

    int nn = 0;
    for (; nn + 2 <= M; nn += 2) {
      int gB = __shfl(lv, nn + 1);
      LOADST(Ba, Bb, Bc, Bd, Bf, gB);       // issue B loads...
      COMPUTE(Aa, Ab, Ac, Ad, Af);          // ...hidden under A compute
      if (nn + 2 < M) {
        int gA2 = __shfl(lv, nn + 2);
        LOADST(Aa, Ab, Ac, Ad, Af, gA2);    // issue next A loads...
      }
      COMPUTE(Ba, Bb, Bc, Bd, Bf);          // ...hidden under B compute
    }
    if (nn < M) COMPUTE(Aa, Ab, Ac, Ad, Af);
  }

  size_t v = ((size_t)i * WW + j) * DD + k;
  float4* o = out + v * 8;
#pragma unroll
  for (int f = 0; f < 8; f++) o[f] = acc[f];
}

extern "C" void kernel_launch(void* const* d_in, const int* in_sizes, int n_in,
                              void* d_out, int out_size, void* d_ws, size_t ws_size,
                              hipStream_t stream) {
  const float* means  = (const float*)d_in[0];
  const float* opac   = (const float*)d_in[1];
  const float* scales = (const float*)d_in[2];
  const float* rots   = (const float*)d_in[3];
  const float4* feats = (const float4*)d_in[4];

  char* ws = (char*)d_ws;
  float4* pack   = (float4*)ws;                       // 512 KB
  int* tileCnt   = (int*)(ws + 512 * 1024);           // 6.4 KB
  int* tileList  = (int*)(ws + 520 * 1024);           // 1.6 MB

  hipMemsetAsync(tileCnt, 0, NTILES * sizeof(int), stream);
  gv_precompute_bin<<<128, 64, 0, stream>>>(means, opac, scales, rots,
                                            pack, tileCnt, tileList);
  dim3 grid(TTZ, TTY, TTX);
  gv_voxelize<<<grid, 256, 0, stream>>>(pack, feats, tileCnt, tileList,
                                        (float4*)d_out);
}

// Round 8
// 128.670 us; speedup vs baseline: 1.6298x; 1.6298x over previous
//
#include <hip/hip_runtime.h>

#define HH 160
#define WW 160
#define DD 16
#define NG 8192
#define VOXEL 0.4f

// tiles: 20 x 20 x 4 (each 8x8x4 voxels) = 1600 tiles
#define TTX 20
#define TTY 20
#define TTZ 4
#define NTILES (TTX * TTY * TTZ)
#define CAP 256   // max survivors per tile (lambda ~61, Poisson max ~110)

// d_ws layout:
//   pack     : 8192 * 4 float4 (64 B/gaussian)   = 512 KB @ 0
//   tileCnt  : NTILES int (6.4 KB)               @ 512 KB
//   tileList : NTILES * CAP int (1.6 MB)         @ 520 KB
// pack per gaussian:
//   p0 = (mu.x, mu.y, mu.z, opacity)
//   p1 = (3sx,  3sy,  3sz,  ci00)
//   p2 = (ci01, ci02, ci11, ci12)
//   p3 = (ci22, 0, 0, 0)

__global__ __launch_bounds__(64) void gv_precompute_bin(
    const float* __restrict__ means, const float* __restrict__ opac,
    const float* __restrict__ scales, const float* __restrict__ rots,
    float4* __restrict__ pack, int* __restrict__ tileCnt,
    int* __restrict__ tileList) {
  int g = blockIdx.x * 64 + threadIdx.x;
  if (g >= NG) return;
  float qw = rots[g * 4 + 0], qx = rots[g * 4 + 1];
  float qy = rots[g * 4 + 2], qz = rots[g * 4 + 3];
  float inv = rsqrtf(qw * qw + qx * qx + qy * qy + qz * qz);
  qw *= inv; qx *= inv; qy *= inv; qz *= inv;
  float R[3][3];
  R[0][0] = 1.f - 2.f * (qy * qy + qz * qz);
  R[0][1] = 2.f * (qx * qy - qw * qz);
  R[0][2] = 2.f * (qx * qz + qw * qy);
  R[1][0] = 2.f * (qx * qy + qw * qz);
  R[1][1] = 1.f - 2.f * (qx * qx + qz * qz);
  R[1][2] = 2.f * (qy * qz - qw * qx);
  R[2][0] = 2.f * (qx * qz - qw * qy);
  R[2][1] = 2.f * (qy * qz + qw * qx);
  R[2][2] = 1.f - 2.f * (qx * qx + qy * qy);
  float sx = scales[g * 3 + 0], sy = scales[g * 3 + 1], sz = scales[g * 3 + 2];
  float s2[3] = {sx * sx, sy * sy, sz * sz};
  float is2[3] = {1.f / s2[0], 1.f / s2[1], 1.f / s2[2]};
  float cov00 = 0.f, cov11 = 0.f, cov22 = 0.f;
  float ci00 = 0.f, ci01 = 0.f, ci02 = 0.f, ci11 = 0.f, ci12 = 0.f, ci22 = 0.f;
#pragma unroll
  for (int c = 0; c < 3; c++) {
    cov00 += R[0][c] * R[0][c] * s2[c];
    cov11 += R[1][c] * R[1][c] * s2[c];
    cov22 += R[2][c] * R[2][c] * s2[c];
    ci00 += R[0][c] * R[0][c] * is2[c];
    ci01 += R[0][c] * R[1][c] * is2[c];
    ci02 += R[0][c] * R[2][c] * is2[c];
    ci11 += R[1][c] * R[1][c] * is2[c];
    ci12 += R[1][c] * R[2][c] * is2[c];
    ci22 += R[2][c] * R[2][c] * is2[c];
  }
  float mx = means[g * 3 + 0], my = means[g * 3 + 1], mz = means[g * 3 + 2];
  float bx = 3.f * sqrtf(cov00), by = 3.f * sqrtf(cov11), bz = 3.f * sqrtf(cov22);
  float4* p = pack + (size_t)g * 4;
  p[0] = make_float4(mx, my, mz, opac[g]);
  p[1] = make_float4(bx, by, bz, ci00);
  p[2] = make_float4(ci01, ci02, ci11, ci12);
  p[3] = make_float4(ci22, 0.f, 0.f, 0.f);

  // voxel-center index ranges covered by bbox (with float-slop margin)
  const float eps = 1e-4f;
  int i0 = (int)ceilf((mx - bx + 32.f) * 2.5f - 0.5f - eps);
  int i1 = (int)floorf((mx + bx + 32.f) * 2.5f - 0.5f + eps);
  int j0 = (int)ceilf((my - by + 32.f) * 2.5f - 0.5f - eps);
  int j1 = (int)floorf((my + by + 32.f) * 2.5f - 0.5f + eps);
  int k0 = (int)ceilf((mz - bz + 1.f) * 2.5f - 0.5f - eps);
  int k1 = (int)floorf((mz + bz + 1.f) * 2.5f - 0.5f + eps);
  i0 = max(i0, 0); i1 = min(i1, HH - 1);
  j0 = max(j0, 0); j1 = min(j1, WW - 1);
  k0 = max(k0, 0); k1 = min(k1, DD - 1);
  if (i0 > i1 || j0 > j1 || k0 > k1) return;
  int ti0 = i0 >> 3, ti1 = i1 >> 3;
  int tj0 = j0 >> 3, tj1 = j1 >> 3;
  int tk0 = k0 >> 2, tk1 = k1 >> 2;
  for (int ti = ti0; ti <= ti1; ti++)
    for (int tj = tj0; tj <= tj1; tj++)
      for (int tk = tk0; tk <= tk1; tk++) {
        int t = (ti * TTY + tj) * TTZ + tk;
        int pos = atomicAdd(&tileCnt[t], 1);
        if (pos < CAP) tileList[t * CAP + pos] = g;
      }
}

// Voxelize: SMEM-broadcast data path (28-VGPR regime, proven R3/R6) with
// TWO latency fixes:
//  1. 8 waves/block: each 64-voxel subset gets TWO waves splitting the tile
//     list odd/even (12800 waves total = 12.5/SIMD) -> independent waves
//     cover each other's lgkmcnt stalls. Pairwise LDS reduce at the end.
//  2. Branchless inner loop: feats s_loads not gated behind the bbox test,
//     so one lgkmcnt wait covers pack+feats (~390 cyc chain, hidden by
//     wave overlap). wgt=0 via cndmask preserves exact semantics.
__global__ __launch_bounds__(512) void gv_voxelize(
    const float4* __restrict__ pack, const float4* __restrict__ feats,
    const int* __restrict__ tileCnt, const int* __restrict__ tileList,
    float4* __restrict__ out) {
  __shared__ float4 s_red[4][64][9];   // [pair][lane][8 data + 1 pad] = 36 KB

  int tid = threadIdx.x;
  int wid = tid >> 6;          // 0..7
  int pair = wid >> 1;         // voxel subset 0..3
  int h = wid & 1;             // list half (0: even idx, 1: odd idx)
  int l = tid & 63;
  // subset covers 4x4x4 voxels: pair -> (i-half, j-half) of the 8x8x4 tile
  int di = (pair >> 1) * 4 + (l >> 4);
  int dj = (pair & 1) * 4 + ((l >> 2) & 3);
  int dk = l & 3;
  int tk = blockIdx.x, tj = blockIdx.y, ti = blockIdx.z;
  int i = ti * 8 + di, j = tj * 8 + dj, k = tk * 4 + dk;

  float px = (i + 0.5f) * VOXEL - 32.f;
  float py = (j + 0.5f) * VOXEL - 32.f;
  float pz = (k + 0.5f) * VOXEL - 1.f;

  int t = (ti * TTY + tj) * TTZ + tk;
  int cnt = tileCnt[t];
  cnt = min(cnt, CAP);
  const int* __restrict__ lst = tileList + t * CAP;

  float4 acc[8];
#pragma unroll
  for (int f = 0; f < 8; f++) acc[f] = make_float4(0.f, 0.f, 0.f, 0.f);

  for (int n = h; n < cnt; n += 2) {
    int gg = __builtin_amdgcn_readfirstlane(lst[n]);
    const float4* __restrict__ p = pack + (size_t)gg * 4;
    const float4* __restrict__ fp = feats + (size_t)gg * 8;
    float4 pa = p[0], pb = p[1], pc = p[2], pd = p[3];
    float4 f0 = fp[0], f1 = fp[1], f2 = fp[2], f3 = fp[3];
    float4 f4 = fp[4], f5 = fp[5], f6 = fp[6], f7 = fp[7];

    float dx = px - pa.x, dy = py - pa.y, dz = pz - pa.z;
    bool in = (fabsf(dx) <= pb.x) & (fabsf(dy) <= pb.y) & (fabsf(dz) <= pb.z);
    float maha = pb.w * dx * dx + pc.z * dy * dy + pd.x * dz * dz +
                 2.f * (pc.x * dx * dy + pc.y * dx * dz + pc.w * dy * dz);
    float wgt = in ? pa.w * __expf(-0.5f * maha) : 0.f;

    acc[0].x += wgt * f0.x; acc[0].y += wgt * f0.y; acc[0].z += wgt * f0.z; acc[0].w += wgt * f0.w;
    acc[1].x += wgt * f1.x; acc[1].y += wgt * f1.y; acc[1].z += wgt * f1.z; acc[1].w += wgt * f1.w;
    acc[2].x += wgt * f2.x; acc[2].y += wgt * f2.y; acc[2].z += wgt * f2.z; acc[2].w += wgt * f2.w;
    acc[3].x += wgt * f3.x; acc[3].y += wgt * f3.y; acc[3].z += wgt * f3.z; acc[3].w += wgt * f3.w;
    acc[4].x += wgt * f4.x; acc[4].y += wgt * f4.y; acc[4].z += wgt * f4.z; acc[4].w += wgt * f4.w;
    acc[5].x += wgt * f5.x; acc[5].y += wgt * f5.y; acc[5].z += wgt * f5.z; acc[5].w += wgt * f5.w;
    acc[6].x += wgt * f6.x; acc[6].y += wgt * f6.y; acc[6].z += wgt * f6.z; acc[6].w += wgt * f6.w;
    acc[7].x += wgt * f7.x; acc[7].y += wgt * f7.y; acc[7].z += wgt * f7.z; acc[7].w += wgt * f7.w;
  }

  // pairwise reduce: odd wave publishes, even wave adds + stores
  if (h) {
#pragma unroll
    for (int f = 0; f < 8; f++) s_red[pair][l][f] = acc[f];
  }
  __syncthreads();
  if (!h) {
    size_t v = ((size_t)i * WW + j) * DD + k;
    float4* o = out + v * 8;
#pragma unroll
    for (int f = 0; f < 8; f++) {
      float4 r = s_red[pair][l][f];
      o[f] = make_float4(acc[f].x + r.x, acc[f].y + r.y,
                         acc[f].z + r.z, acc[f].w + r.w);
    }
  }
}

extern "C" void kernel_launch(void* const* d_in, const int* in_sizes, int n_in,
                              void* d_out, int out_size, void* d_ws, size_t ws_size,
                              hipStream_t stream) {
  const float* means  = (const float*)d_in[0];
  const float* opac   = (const float*)d_in[1];
  const float* scales = (const float*)d_in[2];
  const float* rots   = (const float*)d_in[3];
  const float4* feats = (const float4*)d_in[4];

  char* ws = (char*)d_ws;
  float4* pack   = (float4*)ws;                       // 512 KB
  int* tileCnt   = (int*)(ws + 512 * 1024);           // 6.4 KB
  int* tileList  = (int*)(ws + 520 * 1024);           // 1.6 MB

  hipMemsetAsync(tileCnt, 0, NTILES * sizeof(int), stream);
  gv_precompute_bin<<<128, 64, 0, stream>>>(means, opac, scales, rots,
                                            pack, tileCnt, tileList);
  dim3 grid(TTZ, TTY, TTX);
  gv_voxelize<<<grid, 512, 0, stream>>>(pack, feats, tileCnt, tileList,
                                        (float4*)d_out);
}